// Round 1
// baseline (1573.118 us; speedup 1.0000x reference)
//
#include <hip/hip_runtime.h>
#include <stdint.h>

#define M_DIM 8192
#define K_DIM 4096
#define N_DIM 16384
#define BM 128
#define BN 128
#define BK_L 32   // legacy fallback K-step
#define LDA 40    // legacy padded bf16 row stride

typedef __bf16 bf16x8 __attribute__((ext_vector_type(8)));
typedef float floatx4 __attribute__((ext_vector_type(4)));

union ABFrag { uint32_t u[4]; bf16x8 v; };

typedef const __attribute__((address_space(1))) void* gas_vp;
typedef __attribute__((address_space(3))) void* las_vp;

__device__ __forceinline__ uint32_t bfpack(float a, float b) {
    union { __bf16 h; uint16_t u; } ca, cb;
    ca.h = (__bf16)a; cb.h = (__bf16)b;
    return (uint32_t)ca.u | ((uint32_t)cb.u << 16);
}

// rowsum[m] = sum_k bf16(x[m,k])  -- feeds the zero-point & +128-offset epilogue terms
__global__ __launch_bounds__(256) void rowsum_kernel(const float* __restrict__ x,
                                                     float* __restrict__ rs) {
    const int m = blockIdx.x;
    const int t = threadIdx.x;
    const float4* row = (const float4*)(x + (size_t)m * K_DIM);
    float acc = 0.f;
#pragma unroll
    for (int r = 0; r < K_DIM / (256 * 4); ++r) {
        float4 v = row[r * 256 + t];
        acc += (float)(__bf16)v.x + (float)(__bf16)v.y
             + (float)(__bf16)v.z + (float)(__bf16)v.w;
    }
#pragma unroll
    for (int off = 32; off > 0; off >>= 1) acc += __shfl_down(acc, off, 64);
    __shared__ float sred[4];
    if ((t & 63) == 0) sred[t >> 6] = acc;
    __syncthreads();
    if (t == 0) rs[m] = sred[0] + sred[1] + sred[2] + sred[3];
}

// ---------------------------------------------------------------------------
// Pre-tiled operand layouts (main path).
//
// Chunk permutation (shared by A and B): within one 128-row x 64-k tile,
//   slot(row, kh, q) = (row>>4)*128 + kh*64 + (q>>1)*32 + (row&15)*2 + (q&1)
// where kh = MFMA k-half (0..1), q = lane quad (0..3).
// A: slot indexes 16B chunks (8 bf16, k = kh*32 + q*8 .. +7).
//    ds_read_b128 bank group = slot%8 = (col&3)*2 + (q&1) -> 8 lanes/group, balanced.
// B: slot indexes u32 words (4 packed bytes = 8 nibbles, same k range).
//    ds_read_b32 bank = col*2 + (q&1) -> exactly 2 lanes/bank (free).
// Both tiles are staged with linear global_load_lds (no VALU, no writes).
// ---------------------------------------------------------------------------

// xb layout: [m_blk(64)][kt(64)][1024 slots][16B]  = 64 MiB
__global__ __launch_bounds__(256) void prep_x(const float* __restrict__ x,
                                              uint32_t* __restrict__ xb) {
    const int blk = blockIdx.x;            // m_blk*64 + kt
    const int m_blk = blk >> 6, kt = blk & 63;
    const int tid = threadIdx.x;
    const int row = tid >> 1, kh = tid & 1;
    const float* src = x + (size_t)(m_blk * 128 + row) * K_DIM + kt * 64 + kh * 32;
    uint32_t* dstTile = xb + (size_t)blk * 4096;   // 1024 slots * 4 u32
#pragma unroll
    for (int q = 0; q < 4; ++q) {
        float4 v0 = *(const float4*)(src + q * 8);
        float4 v1 = *(const float4*)(src + q * 8 + 4);
        const int w = ((row >> 4) << 7) + (kh << 6) + ((q >> 1) << 5)
                    + ((row & 15) << 1) + (q & 1);
        uint4 o;
        o.x = bfpack(v0.x, v0.y); o.y = bfpack(v0.z, v0.w);
        o.z = bfpack(v1.x, v1.y); o.w = bfpack(v1.z, v1.w);
        *(uint4*)(dstTile + w * 4) = o;
    }
}

// wb layout: [n_blk(128)][kt(64)][1024 words][4B] = 32 MiB (4 real packed bytes / word)
__global__ __launch_bounds__(256) void prep_w(const int* __restrict__ packed,
                                              uint32_t* __restrict__ wb) {
    const int blk = blockIdx.x;            // n_blk*64 + kt
    const int n_blk = blk >> 6, kt = blk & 63;
    const int tid = threadIdx.x;
    const int row = tid >> 1, kh = tid & 1;
    const int* src = packed + (size_t)(n_blk * 128 + row) * (K_DIM / 2) + kt * 32 + kh * 16;
    uint32_t* dstTile = wb + (size_t)blk * 1024;
    uint32_t u[4];
#pragma unroll
    for (int q = 0; q < 4; ++q) {
        const uint4 p = *(const uint4*)(src + q * 4);
        u[q] = (p.x & 0xFFu) | ((p.y & 0xFFu) << 8) | ((p.z & 0xFFu) << 16) | (p.w << 24);
    }
    const int w0 = ((row >> 4) << 7) + (kh << 6) + ((row & 15) << 1);
    *(uint2*)(dstTile + w0)      = make_uint2(u[0], u[1]);
    *(uint2*)(dstTile + w0 + 32) = make_uint2(u[2], u[3]);
}

// 8 nibbles (one u32 of 4 packed bytes) -> 8 bf16 of (128 + q): 0x4300 | nib
__device__ __forceinline__ void unpack_b(uint32_t w, ABFrag& f) {
    const uint32_t lo = w & 0x0F0F0F0Fu;
    const uint32_t hi = (w >> 4) & 0x0F0F0F0Fu;
    // v_perm_b32: second operand supplies result bytes selected by codes 0-3,
    // first operand by codes 4-7, 0x0C -> 0x00.  byte layout per output word:
    // [lo_j, 0x43, hi_j, 0x43] (low nibble = even k).
    f.u[0] = 0x43004300u | __builtin_amdgcn_perm(hi, lo, 0x0C040C00u);
    f.u[1] = 0x43004300u | __builtin_amdgcn_perm(hi, lo, 0x0C050C01u);
    f.u[2] = 0x43004300u | __builtin_amdgcn_perm(hi, lo, 0x0C060C02u);
    f.u[3] = 0x43004300u | __builtin_amdgcn_perm(hi, lo, 0x0C070C03u);
}

__device__ __forceinline__ void block_sync() {
    __builtin_amdgcn_sched_barrier(0);
    __builtin_amdgcn_s_barrier();
    __builtin_amdgcn_sched_barrier(0);
}

// ---------------------------------------------------------------------------
// Main GEMM: BK=64, double-buffered LDS (A 16K + B 4K per buffer = 40 KiB),
// all staging via global_load_lds, counted vmcnt(5) across raw s_barrier.
// ---------------------------------------------------------------------------
__global__ __launch_bounds__(256, 3) void gemm4bit_t(
    const uint32_t* __restrict__ xb,
    const uint32_t* __restrict__ wb,
    const float* __restrict__ scale,
    const float* __restrict__ zp,
    const float* __restrict__ bias,
    const float* __restrict__ rowsum,
    float* __restrict__ out) {

    __shared__ uint8_t lds[2 * 20480];

    const int tid  = threadIdx.x;
    const int lane = tid & 63;
    const int wv   = tid >> 6;          // 4 waves, 2x2
    const int wm   = wv >> 1;
    const int wn   = wv & 1;
    const int col  = lane & 15;
    const int quad = lane >> 4;

    // supertile swizzle: 8 m-blocks x 16 n-blocks per supertile
    const int bid = blockIdx.x;
    const int sid = bid >> 7;
    const int lid = bid & 127;
    const int m_blk = (sid & 7) * 8 + (lid >> 4);
    const int n_blk = (sid >> 3) * 16 + (lid & 15);
    const int m0 = m_blk * BM;
    const int n0 = n_blk * BN;

    floatx4 acc[4][4];
#pragma unroll
    for (int i = 0; i < 4; ++i)
#pragma unroll
        for (int j = 0; j < 4; ++j) acc[i][j] = (floatx4){0.f, 0.f, 0.f, 0.f};

    // per-thread global staging sources (advance by tile stride per K-iter)
    const uint8_t* aSrc = (const uint8_t*)xb + (size_t)m_blk * (64 * 16384) + tid * 16;
    const uint8_t* bSrc = (const uint8_t*)wb + (size_t)n_blk * (64 * 4096) + tid * 16;

    // fragment LDS byte offsets (within buffer)
    const int slot = (quad >> 1) * 32 + col * 2 + (quad & 1);
    const int aOff = (wm * 512 + slot) * 16;           // + t*2048 + kh*1024
    const int bOff = 16384 + (wn * 512 + slot) * 4;    // + t*512  + kh*256

    auto stage = [&](int buf, int kt) {
        const uint8_t* ab = aSrc + (size_t)kt * 16384;
        const uint8_t* bb = bSrc + (size_t)kt * 4096;
        uint8_t* base = &lds[buf * 20480];
#pragma unroll
        for (int r = 0; r < 4; ++r)
            __builtin_amdgcn_global_load_lds((gas_vp)(ab + r * 4096),
                                             (las_vp)(base + r * 4096 + wv * 1024), 16, 0, 0);
        __builtin_amdgcn_global_load_lds((gas_vp)bb,
                                         (las_vp)(base + 16384 + wv * 1024), 16, 0, 0);
    };

    stage(0, 0);

    for (int kt = 0; kt < 64; ++kt) {
        const int cur = kt & 1;
        if (kt + 1 < 64) {
            stage(cur ^ 1, kt + 1);                // 5 loads stay in flight over compute
            asm volatile("s_waitcnt vmcnt(5)");    // current tile's loads complete
        } else {
            asm volatile("s_waitcnt vmcnt(0)");
        }
        block_sync();

        const uint8_t* ldsA = &lds[cur * 20480];
#pragma unroll
        for (int kh = 0; kh < 2; ++kh) {
            ABFrag a[4], b[4];
#pragma unroll
            for (int t = 0; t < 4; ++t)
                a[t].v = *(const bf16x8*)(ldsA + aOff + t * 2048 + kh * 1024);
#pragma unroll
            for (int t = 0; t < 4; ++t) {
                const uint32_t w = *(const uint32_t*)(ldsA + bOff + t * 512 + kh * 256);
                unpack_b(w, b[t]);
            }
#pragma unroll
            for (int tm = 0; tm < 4; ++tm)
#pragma unroll
                for (int tn = 0; tn < 4; ++tn)
                    acc[tm][tn] = __builtin_amdgcn_mfma_f32_16x16x32_bf16(
                        a[tm].v, b[tn].v, acc[tm][tn], 0, 0, 0);
        }
        block_sync();   // all waves done reading buf before it is overwritten
    }

    // ---- epilogue: out = s*acc + (z - 128*s)*rowsum + bias ----
    float sv[4], av[4], bv[4];
#pragma unroll
    for (int tn = 0; tn < 4; ++tn) {
        const int n = n0 + wn * 64 + tn * 16 + col;
        const float s = scale[n];
        sv[tn] = s;
        av[tn] = zp[n] - 128.f * s;
        bv[tn] = bias[n];
    }
    float rsv[4][4];
#pragma unroll
    for (int tm = 0; tm < 4; ++tm)
#pragma unroll
        for (int r = 0; r < 4; ++r)
            rsv[tm][r] = rowsum[m0 + wm * 64 + tm * 16 + quad * 4 + r];

#pragma unroll
    for (int tm = 0; tm < 4; ++tm) {
#pragma unroll
        for (int r = 0; r < 4; ++r) {
            const int m = m0 + wm * 64 + tm * 16 + quad * 4 + r;
            float* orow = out + (size_t)m * N_DIM + n0 + wn * 64 + col;
#pragma unroll
            for (int tn = 0; tn < 4; ++tn) {
                orow[tn * 16] = sv[tn] * acc[tm][tn][r] + av[tn] * rsv[tm][r] + bv[tn];
            }
        }
    }
}

// ---------------------------------------------------------------------------
// Legacy fallback (proven 2236 us kernel) — used only if workspace too small.
// ---------------------------------------------------------------------------
__global__ __launch_bounds__(256, 3) void gemm4bit(
    const float* __restrict__ x,
    const int* __restrict__ packed,
    const float* __restrict__ scale,
    const float* __restrict__ zp,
    const float* __restrict__ bias,
    const float* __restrict__ rowsum,
    float* __restrict__ out) {

    __shared__ __bf16 As[BM][LDA];
    __shared__ uint32_t Bs[BM * 16];

    const int tid  = threadIdx.x;
    const int lane = tid & 63;
    const int wv   = tid >> 6;
    const int wm   = wv >> 1;
    const int wn   = wv & 1;

    const int bid = blockIdx.x;
    const int sid = bid >> 7;
    const int lid = bid & 127;
    const int m_blk = (sid & 7) * 8 + (lid >> 4);
    const int n_blk = (sid >> 3) * 16 + (lid & 15);
    const int m0 = m_blk * BM;
    const int n0 = n_blk * BN;

    const int arow = tid >> 3;
    const int akq  = tid & 7;

    const int col  = lane & 15;
    const int quad = lane >> 4;

    floatx4 acc[4][4];
#pragma unroll
    for (int i = 0; i < 4; ++i)
#pragma unroll
        for (int j = 0; j < 4; ++j) acc[i][j] = (floatx4){0.f, 0.f, 0.f, 0.f};

    const float* xbase = x + (size_t)m0 * K_DIM;

    for (int it = 0; it < K_DIM / BK_L; ++it) {
        const int k0 = it * BK_L;
#pragma unroll
        for (int r = 0; r < 4; ++r) {
            const int row = r * 32 + arow;
            float4 v = *(const float4*)(xbase + (size_t)row * K_DIM + k0 + akq * 4);
            uint32_t d0 = bfpack(v.x, v.y);
            uint32_t d1 = bfpack(v.z, v.w);
            *(uint2*)&As[row][akq * 4] = make_uint2(d0, d1);
        }
#pragma unroll
        for (int r = 0; r < 2; ++r) {
            const int lin = (r * 4 + wv) * 64 + lane;
            const int row = lin >> 2;
            const int p   = lin & 3;
            const int c   = p ^ ((row >> 1) & 3);
            const int* gp = packed + (size_t)(n0 + row) * (K_DIM / 2) + it * 16 + c * 4;
            uint32_t* lp  = &Bs[(r * 4 + wv) * 256];
            __builtin_amdgcn_global_load_lds((gas_vp)gp, (las_vp)lp, 16, 0, 0);
        }
        __syncthreads();

        ABFrag a[4], b[4];
#pragma unroll
        for (int t = 0; t < 4; ++t) {
            const int mrow = wm * 64 + t * 16 + col;
            a[t].v = *(const bf16x8*)&As[mrow][quad * 8];

            const int nrow = wn * 64 + t * 16 + col;
            const int ch   = quad ^ ((nrow >> 1) & 3);
            uint4 w = *(const uint4*)&Bs[nrow * 16 + ch * 4];
            b[t].u[0] = 0x43004300u | ((w.x & 0xF0u) << 12) | (w.x & 0x0Fu);
            b[t].u[1] = 0x43004300u | ((w.y & 0xF0u) << 12) | (w.y & 0x0Fu);
            b[t].u[2] = 0x43004300u | ((w.z & 0xF0u) << 12) | (w.z & 0x0Fu);
            b[t].u[3] = 0x43004300u | ((w.w & 0xF0u) << 12) | (w.w & 0x0Fu);
        }
#pragma unroll
        for (int tm = 0; tm < 4; ++tm)
#pragma unroll
            for (int tn = 0; tn < 4; ++tn)
                acc[tm][tn] = __builtin_amdgcn_mfma_f32_16x16x32_bf16(
                    a[tm].v, b[tn].v, acc[tm][tn], 0, 0, 0);
        __syncthreads();
    }

    float sv[4], av[4], bv[4];
#pragma unroll
    for (int tn = 0; tn < 4; ++tn) {
        const int n = n0 + wn * 64 + tn * 16 + col;
        const float s = scale[n];
        sv[tn] = s;
        av[tn] = zp[n] - 128.f * s;
        bv[tn] = bias[n];
    }
    float rsv[4][4];
#pragma unroll
    for (int tm = 0; tm < 4; ++tm)
#pragma unroll
        for (int r = 0; r < 4; ++r)
            rsv[tm][r] = rowsum[m0 + wm * 64 + tm * 16 + quad * 4 + r];

#pragma unroll
    for (int tm = 0; tm < 4; ++tm) {
#pragma unroll
        for (int r = 0; r < 4; ++r) {
            const int m = m0 + wm * 64 + tm * 16 + quad * 4 + r;
            float* orow = out + (size_t)m * N_DIM + n0 + wn * 64 + col;
#pragma unroll
            for (int tn = 0; tn < 4; ++tn) {
                orow[tn * 16] = sv[tn] * acc[tm][tn][r] + av[tn] * rsv[tm][r] + bv[tn];
            }
        }
    }
}

extern "C" void kernel_launch(void* const* d_in, const int* in_sizes, int n_in,
                              void* d_out, int out_size, void* d_ws, size_t ws_size,
                              hipStream_t stream) {
    const float* x      = (const float*)d_in[0];
    const int*   packed = (const int*)d_in[1];
    const float* scale  = (const float*)d_in[2];
    const float* zp     = (const float*)d_in[3];
    const float* bias   = (const float*)d_in[4];
    float* out = (float*)d_out;

    const size_t XB = 67108864;   // 8192*4096 bf16, pre-tiled
    const size_t WB = 33554432;   // 16384*2048 bytes, pre-tiled
    const size_t RS = 32768;      // 8192 f32 rowsums

    if (ws_size >= XB + WB + RS) {
        uint32_t* xb = (uint32_t*)d_ws;
        uint32_t* wb = (uint32_t*)((char*)d_ws + XB);
        float*    rs = (float*)((char*)d_ws + XB + WB);
        rowsum_kernel<<<M_DIM, 256, 0, stream>>>(x, rs);
        prep_x<<<64 * 64, 256, 0, stream>>>(x, xb);
        prep_w<<<128 * 64, 256, 0, stream>>>(packed, wb);
        gemm4bit_t<<<(M_DIM / BM) * (N_DIM / BN), 256, 0, stream>>>(
            xb, wb, scale, zp, bias, rs, out);
    } else {
        float* rs = (float*)d_ws;
        rowsum_kernel<<<M_DIM, 256, 0, stream>>>(x, rs);
        gemm4bit<<<(M_DIM / BM) * (N_DIM / BN), 256, 0, stream>>>(
            x, packed, scale, zp, bias, rs, out);
    }
}

// Round 2
// 1530.170 us; speedup vs baseline: 1.0281x; 1.0281x over previous
//
#include <hip/hip_runtime.h>
#include <stdint.h>

#define M_DIM 8192
#define K_DIM 4096
#define N_DIM 16384

// legacy fallback geometry
#define BM_L 128
#define BN_L 128
#define BK_L 32
#define LDA 40

typedef __bf16 bf16x8 __attribute__((ext_vector_type(8)));
typedef float floatx4 __attribute__((ext_vector_type(4)));

union ABFrag { uint32_t u[4]; bf16x8 v; };

typedef const __attribute__((address_space(1))) void* gas_vp;
typedef __attribute__((address_space(3))) void* las_vp;

__device__ __forceinline__ uint32_t bfpack(float a, float b) {
    union { __bf16 h; uint16_t u; } ca, cb;
    ca.h = (__bf16)a; cb.h = (__bf16)b;
    return (uint32_t)ca.u | ((uint32_t)cb.u << 16);
}

// rowsum[m] = sum_k bf16(x[m,k])  (legacy fallback path only)
__global__ __launch_bounds__(256) void rowsum_kernel(const float* __restrict__ x,
                                                     float* __restrict__ rs) {
    const int m = blockIdx.x;
    const int t = threadIdx.x;
    const float4* row = (const float4*)(x + (size_t)m * K_DIM);
    float acc = 0.f;
#pragma unroll
    for (int r = 0; r < K_DIM / (256 * 4); ++r) {
        float4 v = row[r * 256 + t];
        acc += (float)(__bf16)v.x + (float)(__bf16)v.y
             + (float)(__bf16)v.z + (float)(__bf16)v.w;
    }
#pragma unroll
    for (int off = 32; off > 0; off >>= 1) acc += __shfl_down(acc, off, 64);
    __shared__ float sred[4];
    if ((t & 63) == 0) sred[t >> 6] = acc;
    __syncthreads();
    if (t == 0) rs[m] = sred[0] + sred[1] + sred[2] + sred[3];
}

// ---------------------------------------------------------------------------
// Pre-tiled operand layouts (main path).
//
// Chunk permutation within one tile:
//   slot(row, kh, q) = (row>>4)*128 + kh*64 + (q>>1)*32 + (row&15)*2 + (q&1)
// kh = MFMA k-half (0..1), q = lane quad (0..3).
// A (xb): [m_blk(32)][kt(64)][2048 slots][16B] = 64 MiB (rows 0..255/tile).
//   ds_read_b128 16B-group = slot%8 = (2*col+(q&1))%8 -> 8 lanes/group, balanced.
// B (wb): [n_blk(128)][kt(64)][1024 words][4B] = 32 MiB (rows 0..127/tile).
//   ds_read_b32 bank = (2*col+(q&1))%32 -> 2 lanes/bank (free).
// Both tiles staged with linear global_load_lds (no VALU, no LDS writes).
// ---------------------------------------------------------------------------

// Fused prep: blocks [0,2048) convert x -> bf16 tiles + accumulate rowsum;
// blocks [2048,10240) re-pack weights to true bytes in tile order.
__global__ __launch_bounds__(256) void prep_fused(const float* __restrict__ x,
                                                  const int* __restrict__ packed,
                                                  uint32_t* __restrict__ xb,
                                                  uint32_t* __restrict__ wb,
                                                  float* __restrict__ rs) {
    const int b = blockIdx.x;
    const int tid = threadIdx.x;
    if (b < 2048) {
        // ---- x path: tile (m_blk, kt) = 256 rows x 64 k ----
        const int m_blk = b >> 6, kt = b & 63;
        const int kh = tid & 1;
        uint32_t* dstTile = xb + (size_t)b * 8192;   // 2048 slots * 4 u32
#pragma unroll
        for (int r2 = 0; r2 < 2; ++r2) {
            const int row = r2 * 128 + (tid >> 1);
            const float* src = x + (size_t)(m_blk * 256 + row) * K_DIM + kt * 64 + kh * 32;
            float part = 0.f;
#pragma unroll
            for (int q = 0; q < 4; ++q) {
                float4 v0 = *(const float4*)(src + q * 8);
                float4 v1 = *(const float4*)(src + q * 8 + 4);
                const int w = ((row >> 4) << 7) + (kh << 6) + ((q >> 1) << 5)
                            + ((row & 15) << 1) + (q & 1);
                uint4 o;
                o.x = bfpack(v0.x, v0.y); o.y = bfpack(v0.z, v0.w);
                o.z = bfpack(v1.x, v1.y); o.w = bfpack(v1.z, v1.w);
                *(uint4*)(dstTile + w * 4) = o;
                part += (float)(__bf16)v0.x + (float)(__bf16)v0.y
                      + (float)(__bf16)v0.z + (float)(__bf16)v0.w
                      + (float)(__bf16)v1.x + (float)(__bf16)v1.y
                      + (float)(__bf16)v1.z + (float)(__bf16)v1.w;
            }
            part += __shfl_xor(part, 1, 64);      // combine kh pair (adjacent lanes)
            if (kh == 0) atomicAdd(&rs[m_blk * 256 + row], part);
        }
    } else {
        // ---- w path: tile (n_blk, kt) = 128 rows x 64 k (packed nibbles) ----
        const int blk = b - 2048;
        const int n_blk = blk >> 6, kt = blk & 63;
        const int row = tid >> 1, kh = tid & 1;
        const int* src = packed + (size_t)(n_blk * 128 + row) * (K_DIM / 2) + kt * 32 + kh * 16;
        uint32_t* dstTile = wb + (size_t)blk * 1024;
        uint32_t u[4];
#pragma unroll
        for (int q = 0; q < 4; ++q) {
            const uint4 p = *(const uint4*)(src + q * 4);
            u[q] = (p.x & 0xFFu) | ((p.y & 0xFFu) << 8) | ((p.z & 0xFFu) << 16) | (p.w << 24);
        }
        const int w0 = ((row >> 4) << 7) + (kh << 6) + ((row & 15) << 1);
        *(uint2*)(dstTile + w0)      = make_uint2(u[0], u[1]);
        *(uint2*)(dstTile + w0 + 32) = make_uint2(u[2], u[3]);
    }
}

// 8 nibbles (one u32 of 4 packed bytes) -> 8 bf16 of (128 + q): 0x4300 | nib
__device__ __forceinline__ void unpack_b(uint32_t w, ABFrag& f) {
    const uint32_t lo = w & 0x0F0F0F0Fu;
    const uint32_t hi = (w >> 4) & 0x0F0F0F0Fu;
    f.u[0] = 0x43004300u | __builtin_amdgcn_perm(hi, lo, 0x0C040C00u);
    f.u[1] = 0x43004300u | __builtin_amdgcn_perm(hi, lo, 0x0C050C01u);
    f.u[2] = 0x43004300u | __builtin_amdgcn_perm(hi, lo, 0x0C060C02u);
    f.u[3] = 0x43004300u | __builtin_amdgcn_perm(hi, lo, 0x0C070C03u);
}

__device__ __forceinline__ void block_sync() {
    __builtin_amdgcn_sched_barrier(0);
    __builtin_amdgcn_s_barrier();
    __builtin_amdgcn_sched_barrier(0);
}

// ---------------------------------------------------------------------------
// Main GEMM: 256x128 block, 4 waves of 128m x 64n (acc 8x4), BK=64.
// M-tall wave tile: 8 B-words unpacked per wave feed 64 MFMAs (was 32).
// Double-buffered LDS (A 32K + B 4K per buffer = 72 KiB), staging via
// global_load_lds, counted vmcnt(9) across raw s_barrier.
// ---------------------------------------------------------------------------
__global__ __launch_bounds__(256, 2) void gemm4bit_t(
    const uint32_t* __restrict__ xb,
    const uint32_t* __restrict__ wb,
    const float* __restrict__ scale,
    const float* __restrict__ zp,
    const float* __restrict__ bias,
    const float* __restrict__ rowsum,
    float* __restrict__ out) {

    __shared__ uint8_t lds[2 * 36864];

    const int tid  = threadIdx.x;
    const int lane = tid & 63;
    const int wv   = tid >> 6;          // 4 waves: 2(m) x 2(n)
    const int wm   = wv >> 1;
    const int wn   = wv & 1;
    const int col  = lane & 15;
    const int quad = lane >> 4;

    // supertile swizzle: 8 m-blocks x 16 n-blocks per supertile
    const int bid = blockIdx.x;
    const int sid = bid >> 7;
    const int lid = bid & 127;
    const int m_blk = (sid & 3) * 8 + (lid >> 4);      // 0..31
    const int n_blk = (sid >> 2) * 16 + (lid & 15);    // 0..127
    const int m0 = m_blk * 256;
    const int n0 = n_blk * 128;

    floatx4 acc[8][4];
#pragma unroll
    for (int i = 0; i < 8; ++i)
#pragma unroll
        for (int j = 0; j < 4; ++j) acc[i][j] = (floatx4){0.f, 0.f, 0.f, 0.f};

    const uint8_t* aSrc = (const uint8_t*)xb + (size_t)m_blk * (64 * 32768) + tid * 16;
    const uint8_t* bSrc = (const uint8_t*)wb + (size_t)n_blk * (64 * 4096) + tid * 16;

    // fragment LDS byte offsets (within buffer)
    const int sl16 = ((quad >> 1) * 32 + col * 2 + (quad & 1)) * 16;
    const int aOff = wm * 16384 + sl16;                 // + t*2048 + kh*1024
    const int bOff = 32768 + wn * 2048 + (sl16 >> 2);   // + t*512  + kh*256

    auto stage = [&](int buf, int kt) {
        const uint8_t* ab = aSrc + (size_t)kt * 32768;
        const uint8_t* bb = bSrc + (size_t)kt * 4096;
        uint8_t* base = &lds[buf * 36864];
#pragma unroll
        for (int r = 0; r < 8; ++r)
            __builtin_amdgcn_global_load_lds((gas_vp)(ab + r * 4096),
                                             (las_vp)(base + r * 4096 + wv * 1024), 16, 0, 0);
        __builtin_amdgcn_global_load_lds((gas_vp)bb,
                                         (las_vp)(base + 32768 + wv * 1024), 16, 0, 0);
    };

    stage(0, 0);

    for (int kt = 0; kt < 64; ++kt) {
        const int cur = kt & 1;
        if (kt + 1 < 64) {
            stage(cur ^ 1, kt + 1);                // 9 loads stay in flight over compute
            asm volatile("s_waitcnt vmcnt(9)");    // current tile's loads complete
        } else {
            asm volatile("s_waitcnt vmcnt(0)");
        }
        block_sync();

        const uint8_t* ldsA = &lds[cur * 36864];
#pragma unroll
        for (int kh = 0; kh < 2; ++kh) {
            ABFrag a[8], b[4];
#pragma unroll
            for (int t = 0; t < 8; ++t)
                a[t].v = *(const bf16x8*)(ldsA + aOff + t * 2048 + kh * 1024);
#pragma unroll
            for (int t = 0; t < 4; ++t)
                unpack_b(*(const uint32_t*)(ldsA + bOff + t * 512 + kh * 256), b[t]);
#pragma unroll
            for (int tm = 0; tm < 8; ++tm)
#pragma unroll
                for (int tn = 0; tn < 4; ++tn)
                    acc[tm][tn] = __builtin_amdgcn_mfma_f32_16x16x32_bf16(
                        a[tm].v, b[tn].v, acc[tm][tn], 0, 0, 0);
        }
        block_sync();   // all waves done reading buf before it is overwritten
    }

    // ---- epilogue: out = s*acc + (z - 128*s)*rowsum + bias ----
    float sv[4], av[4], bv[4];
#pragma unroll
    for (int tn = 0; tn < 4; ++tn) {
        const int n = n0 + wn * 64 + tn * 16 + col;
        const float s = scale[n];
        sv[tn] = s;
        av[tn] = zp[n] - 128.f * s;
        bv[tn] = bias[n];
    }

#pragma unroll
    for (int tm = 0; tm < 8; ++tm) {
#pragma unroll
        for (int r = 0; r < 4; ++r) {
            const int m = m0 + wm * 128 + tm * 16 + quad * 4 + r;
            const float rsm = rowsum[m];
            float* orow = out + (size_t)m * N_DIM + n0 + wn * 64 + col;
#pragma unroll
            for (int tn = 0; tn < 4; ++tn) {
                orow[tn * 16] = sv[tn] * acc[tm][tn][r] + av[tn] * rsm + bv[tn];
            }
        }
    }
}

// ---------------------------------------------------------------------------
// Legacy fallback (proven kernel) — used only if workspace too small.
// ---------------------------------------------------------------------------
__global__ __launch_bounds__(256, 3) void gemm4bit(
    const float* __restrict__ x,
    const int* __restrict__ packed,
    const float* __restrict__ scale,
    const float* __restrict__ zp,
    const float* __restrict__ bias,
    const float* __restrict__ rowsum,
    float* __restrict__ out) {

    __shared__ __bf16 As[BM_L][LDA];
    __shared__ uint32_t Bs[BM_L * 16];

    const int tid  = threadIdx.x;
    const int lane = tid & 63;
    const int wv   = tid >> 6;
    const int wm   = wv >> 1;
    const int wn   = wv & 1;

    const int bid = blockIdx.x;
    const int sid = bid >> 7;
    const int lid = bid & 127;
    const int m_blk = (sid & 7) * 8 + (lid >> 4);
    const int n_blk = (sid >> 3) * 16 + (lid & 15);
    const int m0 = m_blk * BM_L;
    const int n0 = n_blk * BN_L;

    const int arow = tid >> 3;
    const int akq  = tid & 7;

    const int col  = lane & 15;
    const int quad = lane >> 4;

    floatx4 acc[4][4];
#pragma unroll
    for (int i = 0; i < 4; ++i)
#pragma unroll
        for (int j = 0; j < 4; ++j) acc[i][j] = (floatx4){0.f, 0.f, 0.f, 0.f};

    const float* xbase = x + (size_t)m0 * K_DIM;

    for (int it = 0; it < K_DIM / BK_L; ++it) {
        const int k0 = it * BK_L;
#pragma unroll
        for (int r = 0; r < 4; ++r) {
            const int row = r * 32 + arow;
            float4 v = *(const float4*)(xbase + (size_t)row * K_DIM + k0 + akq * 4);
            uint32_t d0 = bfpack(v.x, v.y);
            uint32_t d1 = bfpack(v.z, v.w);
            *(uint2*)&As[row][akq * 4] = make_uint2(d0, d1);
        }
#pragma unroll
        for (int r = 0; r < 2; ++r) {
            const int lin = (r * 4 + wv) * 64 + lane;
            const int row = lin >> 2;
            const int p   = lin & 3;
            const int c   = p ^ ((row >> 1) & 3);
            const int* gp = packed + (size_t)(n0 + row) * (K_DIM / 2) + it * 16 + c * 4;
            uint32_t* lp  = &Bs[(r * 4 + wv) * 256];
            __builtin_amdgcn_global_load_lds((gas_vp)gp, (las_vp)lp, 16, 0, 0);
        }
        __syncthreads();

        ABFrag a[4], b[4];
#pragma unroll
        for (int t = 0; t < 4; ++t) {
            const int mrow = wm * 64 + t * 16 + col;
            a[t].v = *(const bf16x8*)&As[mrow][quad * 8];

            const int nrow = wn * 64 + t * 16 + col;
            const int ch   = quad ^ ((nrow >> 1) & 3);
            uint4 w = *(const uint4*)&Bs[nrow * 16 + ch * 4];
            b[t].u[0] = 0x43004300u | ((w.x & 0xF0u) << 12) | (w.x & 0x0Fu);
            b[t].u[1] = 0x43004300u | ((w.y & 0xF0u) << 12) | (w.y & 0x0Fu);
            b[t].u[2] = 0x43004300u | ((w.z & 0xF0u) << 12) | (w.z & 0x0Fu);
            b[t].u[3] = 0x43004300u | ((w.w & 0xF0u) << 12) | (w.w & 0x0Fu);
        }
#pragma unroll
        for (int tm = 0; tm < 4; ++tm)
#pragma unroll
            for (int tn = 0; tn < 4; ++tn)
                acc[tm][tn] = __builtin_amdgcn_mfma_f32_16x16x32_bf16(
                    a[tm].v, b[tn].v, acc[tm][tn], 0, 0, 0);
        __syncthreads();
    }

    float sv[4], av[4], bv[4];
#pragma unroll
    for (int tn = 0; tn < 4; ++tn) {
        const int n = n0 + wn * 64 + tn * 16 + col;
        const float s = scale[n];
        sv[tn] = s;
        av[tn] = zp[n] - 128.f * s;
        bv[tn] = bias[n];
    }
#pragma unroll
    for (int tm = 0; tm < 4; ++tm) {
#pragma unroll
        for (int r = 0; r < 4; ++r) {
            const int m = m0 + wm * 64 + tm * 16 + quad * 4 + r;
            const float rsm = rowsum[m];
            float* orow = out + (size_t)m * N_DIM + n0 + wn * 64 + col;
#pragma unroll
            for (int tn = 0; tn < 4; ++tn) {
                orow[tn * 16] = sv[tn] * acc[tm][tn][r] + av[tn] * rsm + bv[tn];
            }
        }
    }
}

extern "C" void kernel_launch(void* const* d_in, const int* in_sizes, int n_in,
                              void* d_out, int out_size, void* d_ws, size_t ws_size,
                              hipStream_t stream) {
    const float* x      = (const float*)d_in[0];
    const int*   packed = (const int*)d_in[1];
    const float* scale  = (const float*)d_in[2];
    const float* zp     = (const float*)d_in[3];
    const float* bias   = (const float*)d_in[4];
    float* out = (float*)d_out;

    const size_t XB = 67108864;   // 8192*4096 bf16, pre-tiled (32 m-blocks x 64 kt)
    const size_t WB = 33554432;   // 16384*2048 bytes, pre-tiled (128 n-blocks x 64 kt)
    const size_t RS = 32768;      // 8192 f32 rowsums

    if (ws_size >= XB + WB + RS) {
        uint32_t* xb = (uint32_t*)d_ws;
        uint32_t* wb = (uint32_t*)((char*)d_ws + XB);
        float*    rs = (float*)((char*)d_ws + XB + WB);
        hipMemsetAsync(rs, 0, RS, stream);
        prep_fused<<<2048 + 8192, 256, 0, stream>>>(x, packed, xb, wb, rs);
        gemm4bit_t<<<(M_DIM / 256) * (N_DIM / 128), 256, 0, stream>>>(
            xb, wb, scale, zp, bias, rs, out);
    } else {
        float* rs = (float*)d_ws;
        rowsum_kernel<<<M_DIM, 256, 0, stream>>>(x, rs);
        gemm4bit<<<(M_DIM / BM_L) * (N_DIM / BN_L), 256, 0, stream>>>(
            x, packed, scale, zp, bias, rs, out);
    }
}